// Round 4
// baseline (331.649 us; speedup 1.0000x reference)
//
#include <hip/hip_runtime.h>
#include <hip/hip_bf16.h>

typedef __hip_bfloat16 bf16;
typedef float v4f __attribute__((ext_vector_type(4)));
typedef short v8s __attribute__((ext_vector_type(8)));

typedef const __attribute__((address_space(1))) void gvoid;
typedef __attribute__((address_space(3))) void lvoid;

__device__ __forceinline__ void async16(const void* g, void* l) {
  __builtin_amdgcn_global_load_lds((gvoid*)g, (lvoid*)l, 16, 0, 0);
}

__device__ __forceinline__ unsigned short f2bf(float v) {
  __hip_bfloat16 h = __float2bfloat16(v);
  return *(unsigned short*)&h;
}
__device__ __forceinline__ float bflo(unsigned dw) {
  unsigned u = dw << 16;
  return *(float*)&u;
}
__device__ __forceinline__ float bfhi(unsigned dw) {
  unsigned u = dw & 0xffff0000u;
  return *(float*)&u;
}

// cardinal cubic B-spline on [0,4], 0 outside. Reference bspline(t) == b3(4t),
// wavelet(t) == b3(8t) - b3(8t-4). Clamp makes u>=4 exactly 0 (64-108+48-4).
__device__ __forceinline__ float b3(float u) {
  u = fminf(fmaxf(u, 0.f), 4.f);
  float t1 = fmaxf(u - 1.f, 0.f);
  float t2 = fmaxf(u - 2.f, 0.f);
  float t3 = fmaxf(u - 3.f, 0.f);
  float c0 = u * u * u;
  float c1 = t1 * t1 * t1;
  float c2 = t2 * t2 * t2;
  float c3 = t3 * t3 * t3;
  return (c0 - 4.f * c1 + 6.f * c2 - 4.f * c3) * (1.f / 6.f);
}

// m97-style NT GEMM mainloop (used by gemm_proj): C[128 x NI*32] tile.
template <int NI, int BK>
__device__ __forceinline__ void mfma_loop(const bf16* __restrict__ A,
                                          const bf16* __restrict__ B, int lda,
                                          int ldb, int kLen, bf16* As, bf16* Bs,
                                          v4f acc[4][NI]) {
  const int tid = threadIdx.x;
  const int wave = tid >> 6;
  const int lane = tid & 63;
  const int quad = lane >> 4;
  const int r16 = lane & 15;
  const int wm = (wave >> 1) * 64;
  const int wn = (wave & 1) * (NI * 16);
  constexpr int CPR = BK / 8;          // 16B chunks per row
  constexpr int AQ = 128 * CPR / 256;  // async groups for A
  constexpr int BQ = NI * 32 * CPR / 256;
  char* AsC = (char*)As;
  char* BsC = (char*)Bs;
  for (int kk = 0; kk < kLen; kk += BK) {
#pragma unroll
    for (int q = 0; q < AQ; ++q) {
      const int ch = tid + 256 * q;
      const int r = ch / CPR, c = (ch % CPR) * 8;
      async16(A + (size_t)r * lda + kk + c, AsC + q * 4096 + wave * 1024);
    }
#pragma unroll
    for (int q = 0; q < BQ; ++q) {
      const int ch = tid + 256 * q;
      const int r = ch / CPR, c = (ch % CPR) * 8;
      async16(B + (size_t)r * ldb + kk + c, BsC + q * 4096 + wave * 1024);
    }
    __syncthreads();
#pragma unroll
    for (int ks = 0; ks < BK / 32; ++ks) {
      v8s af[4], bfr[NI];
#pragma unroll
      for (int mi = 0; mi < 4; ++mi)
        af[mi] =
            *(const v8s*)(As + (wm + mi * 16 + r16) * BK + ks * 32 + quad * 8);
#pragma unroll
      for (int ni = 0; ni < NI; ++ni)
        bfr[ni] =
            *(const v8s*)(Bs + (wn + ni * 16 + r16) * BK + ks * 32 + quad * 8);
#pragma unroll
      for (int mi = 0; mi < 4; ++mi)
#pragma unroll
        for (int ni = 0; ni < NI; ++ni)
          acc[mi][ni] = __builtin_amdgcn_mfma_f32_16x16x32_bf16(
              af[mi], bfr[ni], acc[mi][ni], 0, 0, 0);
    }
    __syncthreads();
  }
}

// per-row: sq-norm + bf16 cast of x into U[:, 0:256]
__global__ void prep(const float* __restrict__ x, bf16* __restrict__ U,
                     float* __restrict__ sq) {
  const int n = blockIdx.x, b = blockIdx.y, t = threadIdx.x;
  const size_t row = (size_t)b * 4096 + n;
  float v = x[row * 256 + t];
  U[row * 1280 + t] = __float2bfloat16(v);
  float s = v * v;
#pragma unroll
  for (int o = 32; o > 0; o >>= 1) s += __shfl_down(s, o, 64);
  __shared__ float ls[4];
  if ((t & 63) == 0) ls[t >> 6] = s;
  __syncthreads();
  if (t == 0) sq[row] = ls[0] + ls[1] + ls[2] + ls[3];
}

// fp32 [z][4096][256] -> bf16 [z][256][4096] (tiled transpose via LDS)
__global__ void transk(const float* __restrict__ src, bf16* __restrict__ dst) {
  __shared__ float tile[64][65];
  const int z = blockIdx.z;
  const float* s = src + (size_t)z * 4096 * 256;
  bf16* d = dst + (size_t)z * 256 * 4096;
  const int n0 = blockIdx.x * 64, d0 = blockIdx.y * 64;
  const int tx = threadIdx.x & 31, ty = threadIdx.x >> 5;
#pragma unroll
  for (int i = 0; i < 8; ++i) {
    const int r = ty + i * 8;
    const float2 v = *(const float2*)(s + (size_t)(n0 + r) * 256 + d0 + tx * 2);
    tile[r][tx * 2] = v.x;
    tile[r][tx * 2 + 1] = v.y;
  }
  __syncthreads();
#pragma unroll
  for (int i = 0; i < 8; ++i) {
    const int c = ty + i * 8;
    __hip_bfloat162 p;
    p.x = __float2bfloat16(tile[tx * 2][c]);
    p.y = __float2bfloat16(tile[tx * 2 + 1][c]);
    *(__hip_bfloat162*)(d + (size_t)(d0 + c) * 4096 + n0 + tx * 2) = p;
  }
}

// WbigT bf16 [128][1280]
__global__ void wbig(const float* __restrict__ Wk, const float* __restrict__ Wl,
                     bf16* __restrict__ WbT) {
  int idx = blockIdx.x * 256 + threadIdx.x;
  if (idx >= 128 * 1280) return;
  int j = idx / 1280, k = idx % 1280;
  int o = j & 63;
  float v = 0.f;
  if (k < 256)
    v = Wk[k * 64 + o] + Wl[k * 128 + j];
  else if (k < 512)
    v = (j < 64) ? Wk[16384 + (k - 256) * 64 + o] : 0.f;
  else if (k < 768)
    v = (j < 64) ? Wk[32768 + (k - 512) * 64 + o] : 0.f;
  else if (k < 1024)
    v = (j >= 64) ? Wk[16384 + (k - 768) * 64 + o] : 0.f;
  else
    v = (j >= 64) ? Wk[32768 + (k - 1024) * 64 + o] : 0.f;
  WbT[idx] = __float2bfloat16(v);
}

// Fused flash-style pass, v3 (LDS-pipe relief). v2 was LDS-bound: 80
// ds_read_b128 per 96 MFMA per wave per jt (~8x LDS-over-MFMA per CU).
// Changes vs v2:
//  - Xi (S A-operand, block-invariant) hoisted to REGISTERS (16 one-time
//    global dwordx4/lane): kills 32 reads/jt/wave, frees 32K LDS.
//  - PV transposed: h^T[d][i] = mfma(A=Vt[d][j], B=P[i][j]); wave-tile
//    64d x 64i (16 MFMA / 8 reads, ratio 2.0). Waves split by KERNEL
//    (grp=wave>>2: 0->Pb, 1->Pw), so no split-K merge, and one Vt stage
//    feeds both kernels when Vb==Vw (pass 1).
//  - Vt pair-line layout (two 64B d-rows per 128B line, 3-bit XOR):
//    full 8-slot spread (v2's 2-bit XOR left a 4-way conflict).
//  - 9 barriers/jt (was 13). Reads/jt/wave 80 -> 48.
// hpart is now [d][4096 i] per slab (reduceT adapted). FP order of every
// accumulation identical to v2.
// LDS: Xj 2x16K + Vt 2buf x 2plane x 16K + Pb/Pw 32K + lut 8K = 136 KB.
__global__ __launch_bounds__(512, 2) void fused_kh(
    const bf16* __restrict__ U, const float* __restrict__ sqv,
    const bf16* __restrict__ VbB, const bf16* __restrict__ VwB, int bmul,
    bf16* __restrict__ hpart) {
  __shared__ __align__(16) bf16 Xj[2][128 * 64];     // swz8: rows 128B
  __shared__ __align__(16) bf16 Vt[2][2][256 * 32];  // pair-line swz8
  __shared__ __align__(16) bf16 Pb[64 * 128];        // swz8: rows 256B
  __shared__ __align__(16) bf16 Pw[64 * 128];        // swz8
  __shared__ unsigned lut[2048];

  const int tid = threadIdx.x;
  const int wave = tid >> 6, lane = tid & 63;
  const int quad = lane >> 4, r16 = lane & 15;
  const int par = lane & 1;
  const int grp = wave >> 2;        // S row-group AND PV kernel group
  const int wm = grp * 32;          // S row tile (i)
  const int wns = (wave & 3) * 32;  // S col tile (j)
  const int d0 = (wave & 3) * 64;   // PV d tile
  const int i0 = blockIdx.x * 64;
  const int split = blockIdx.y;
  const int b = blockIdx.z;
  const int vsel = bmul - 1;  // 0: shared V plane (pass1), 1: per-kern planes

  for (int i = tid; i < 2048; i += 512) {
    float t = (i + 0.5f) * (1.f / 2048.f);
    float bv = b3(4.f * t);
    float wv = b3(8.f * t) - b3(8.f * t - 4.f);
    lut[i] = (unsigned)f2bf(bv) | ((unsigned)f2bf(wv) << 16);
  }

  const bf16* Vb = VbB + (size_t)b * bmul * 256 * 4096;
  const bf16* Vw = VwB + (size_t)b * bmul * 256 * 4096;
  const bf16* Ub = U + (size_t)b * 4096 * 1280;

  // stage one K-quarter (64 cols) of Xj rows [j0g, j0g+128) into Xj[buf]
  auto stageXj = [&](int buf, int j0g, int kq) {
    char* C = (char*)Xj[buf];
    const bf16* src = Ub + (size_t)j0g * 1280 + kq * 64;
#pragma unroll
    for (int q = 0; q < 2; ++q) {
      const int ch = tid + 512 * q;
      const int r = ch >> 3, cp = ch & 7;
      async16(src + (size_t)r * 1280 + ((cp ^ (r & 7)) << 3),
              C + q * 8192 + wave * 1024);
    }
  };
  // stage Vt[buf][*] = V^T[0:256][j0g + jc*32 ..+32), pair-line swizzled:
  // LDS line l slot s holds (d = 2l + (c>>2), jq = c&3) with c = s ^ (l&7).
  auto stageVt = [&](int buf, int jc, int j0g) {
    char* C = (char*)(&Vt[buf][0][0]);
    for (int p = 0; p < 1 + vsel; ++p) {
      const bf16* src = (p ? Vw : Vb) + j0g + jc * 32;
#pragma unroll
      for (int q = 0; q < 2; ++q) {
        const int ch = tid + 512 * q;
        const int line = ch >> 3, slot = ch & 7;
        const int c = slot ^ (line & 7);
        const int d = line * 2 + (c >> 2);
        async16(src + (size_t)d * 4096 + ((c & 3) << 3),
                C + p * 16384 + q * 8192 + wave * 1024);
      }
    }
  };

  // prologue: first Xj quarter + Xi rows -> registers (one-time)
  stageXj(0, split * 1024, 0);
  v8s xi[2][8];  // Xi[wm + mi*16 + r16][chunk (ck>>1)*8 + (ck&1)*4 + quad]
  {
    const bf16* src = Ub + (size_t)(i0 + wm) * 1280;
#pragma unroll
    for (int mi = 0; mi < 2; ++mi)
#pragma unroll
      for (int ck = 0; ck < 8; ++ck)
        xi[mi][ck] = *(const v8s*)(src + (size_t)(mi * 16 + r16) * 1280 +
                                   ((ck >> 1) * 8 + (ck & 1) * 4 + quad) * 8);
  }

  const float* sqr = sqv + b * 4096;
  float sqi[8];
#pragma unroll
  for (int mi = 0; mi < 2; ++mi)
#pragma unroll
    for (int r = 0; r < 4; ++r)
      sqi[mi * 4 + r] = sqr[i0 + wm + mi * 16 + quad * 4 + r];

  v4f acc[4][4];  // PV acc: h^T[d0 + mi*16][i0 + ni*16], this wave's kernel
#pragma unroll
  for (int mi = 0; mi < 4; ++mi)
#pragma unroll
    for (int ni = 0; ni < 4; ++ni) acc[mi][ni] = (v4f){0.f, 0.f, 0.f, 0.f};

  const float cexp = -1.4426950408889634f / 512.f;  // -log2(e)/512
  __syncthreads();  // lut + Xj[0] ready

  for (int jt = 0; jt < 8; ++jt) {
    const int j0g = split * 1024 + jt * 128;
    float sqj[2];
#pragma unroll
    for (int ni = 0; ni < 2; ++ni) sqj[ni] = sqr[j0g + wns + ni * 16 + r16];

    // ---- S phase: accs = Xi(regs) @ Xj^T over 4 K-quarters, ping-pong ----
    v4f accs[2][2];
#pragma unroll
    for (int mi = 0; mi < 2; ++mi)
#pragma unroll
      for (int ni = 0; ni < 2; ++ni) accs[mi][ni] = (v4f){0.f, 0.f, 0.f, 0.f};
#pragma unroll
    for (int kq = 0; kq < 4; ++kq) {
      if (kq < 3)
        stageXj((kq + 1) & 1, j0g, kq + 1);
      else
        stageVt(0, 0, j0g);  // first PV stage prefetch
      const bf16* Xq = Xj[kq & 1];
      __builtin_amdgcn_s_setprio(1);
#pragma unroll
      for (int ks = 0; ks < 2; ++ks) {
        v8s bfr[2];
#pragma unroll
        for (int ni = 0; ni < 2; ++ni) {
          const int row = wns + ni * 16 + r16;
          const int ck = ks * 4 + quad;
          bfr[ni] = *(const v8s*)(Xq + row * 64 + ((ck ^ (row & 7)) << 3));
        }
#pragma unroll
        for (int mi = 0; mi < 2; ++mi)
#pragma unroll
          for (int ni = 0; ni < 2; ++ni)
            accs[mi][ni] = __builtin_amdgcn_mfma_f32_16x16x32_bf16(
                xi[mi][kq * 2 + ks], bfr[ni], accs[mi][ni], 0, 0, 0);
      }
      __builtin_amdgcn_s_setprio(0);
      __syncthreads();
    }
    // ---- spline epilogue: d2 -> LUT -> P_b,P_w into LDS (swizzled) ----
#pragma unroll
    for (int mi = 0; mi < 2; ++mi) {
#pragma unroll
      for (int ni = 0; ni < 2; ++ni) {
        unsigned pv[4];
#pragma unroll
        for (int r = 0; r < 4; ++r) {
          float s = accs[mi][ni][r];
          float d2 = fmaxf(sqi[mi * 4 + r] + sqj[ni] - 2.f * s, 0.f);
          float t = __builtin_amdgcn_exp2f(d2 * cexp);
          int idx = (int)fminf(t * 2048.f, 2047.f);
          pv[r] = lut[idx];
        }
        unsigned ov[4];
#pragma unroll
        for (int r = 0; r < 4; ++r) ov[r] = __shfl_xor((int)pv[r], 1, 64);
#pragma unroll
        for (int rr = 0; rr < 2; ++rr) {
          const int r = par * 2 + rr;
          const unsigned ea = pv[r], eb = ov[r];
          const unsigned lo = par ? eb : ea;  // even column
          const unsigned hi = par ? ea : eb;  // odd column
          const int row = wm + mi * 16 + quad * 4 + r;
          const int colp = wns + ni * 16 + (r16 & ~1);
          const int eoff =
              row * 128 + (((colp >> 3) ^ (row & 7)) << 3) + (colp & 7);
          *(unsigned*)(Pb + eoff) = (lo & 0xffffu) | (hi << 16);
          *(unsigned*)(Pw + eoff) = (lo >> 16) | (hi & 0xffff0000u);
        }
      }
    }
    stageVt(1, 1, j0g);  // second PV stage, lands during epilogue drain
    __syncthreads();     // P visible; Vt[0] ready
    // ---- PV phase: acc += Vt @ P^T, 4 j-chunks of 32, ping-pong Vt ----
    const bf16* P = grp ? Pw : Pb;
    const int vp = grp * vsel;  // V plane for this kernel group
#pragma unroll
    for (int jc = 0; jc < 4; ++jc) {
      if (jc == 1)
        stageVt(0, 2, j0g);
      else if (jc == 2)
        stageVt(1, 3, j0g);
      else if (jc == 3 && jt < 7)
        stageXj(0, j0g + 128, 0);  // next jt's first quarter
      const bf16* Vq = &Vt[jc & 1][vp][0];
      __builtin_amdgcn_s_setprio(1);
      v8s va[4], pb_[4];
#pragma unroll
      for (int mi = 0; mi < 4; ++mi) {
        const int d = d0 + mi * 16 + r16;
        const int line = d >> 1;
        const int c = (d & 1) * 4 + quad;
        va[mi] = *(const v8s*)(Vq + line * 64 + ((c ^ (line & 7)) << 3));
      }
#pragma unroll
      for (int ni = 0; ni < 4; ++ni) {
        const int row = ni * 16 + r16;
        const int ck = jc * 4 + quad;
        pb_[ni] = *(const v8s*)(P + row * 128 + ((ck ^ (row & 7)) << 3));
      }
#pragma unroll
      for (int mi = 0; mi < 4; ++mi)
#pragma unroll
        for (int ni = 0; ni < 4; ++ni)
          acc[mi][ni] = __builtin_amdgcn_mfma_f32_16x16x32_bf16(
              va[mi], pb_[ni], acc[mi][ni], 0, 0, 0);
      __builtin_amdgcn_s_setprio(0);
      __syncthreads();
    }
  }
  // ---- write bf16 partials: H[d][i], packed i-pairs, dword stores ----
  bf16* H = hpart + ((size_t)split * 4 + b * 2 + grp) * 4096 * 256;
#pragma unroll
  for (int mi = 0; mi < 4; ++mi) {
#pragma unroll
    for (int ni = 0; ni < 4; ++ni) {
      unsigned pv[4];
#pragma unroll
      for (int r = 0; r < 4; ++r) pv[r] = (unsigned)f2bf(acc[mi][ni][r]);
      unsigned ov[4];
#pragma unroll
      for (int r = 0; r < 4; ++r) ov[r] = __shfl_xor((int)pv[r], 1, 64);
#pragma unroll
      for (int rr = 0; rr < 2; ++rr) {
        const int r = par * 2 + rr;
        const unsigned ea = pv[r], eb = ov[r];
        const unsigned lo = par ? eb : ea;
        const unsigned hi = par ? ea : eb;
        const int d = d0 + mi * 16 + quad * 4 + r;
        const int ic = i0 + ni * 16 + (r16 & ~1);
        *(unsigned*)(H + (size_t)d * 4096 + ic) = lo | (hi << 16);
      }
    }
  }
}

// sum the four bf16 split-K partials (now [256 d][4096 n] slabs); write
// bf16 slice into U[:, uoff..] (transposing via LDS) and (pass 1 only)
// direct bf16 copy into hT [z][256][4096].
__global__ void reduceT(const bf16* __restrict__ hpart, bf16* __restrict__ U,
                        bf16* __restrict__ hT, int uoffBase) {
  __shared__ float tile[64][65];  // [d-local][n-local]
  const int z = blockIdx.z;
  const int b = z >> 1, kern = z & 1;
  const int uoff = uoffBase + kern * 512;
  const int n0 = blockIdx.x * 64, d0 = blockIdx.y * 64;
  const int tx = threadIdx.x & 31, ty = threadIdx.x >> 5;
  const size_t sstride = (size_t)4 * 4096 * 256;
  const bf16* s0 = hpart + (size_t)z * 4096 * 256;
#pragma unroll
  for (int i = 0; i < 8; ++i) {
    const int dl = ty + i * 8;
    const size_t off = (size_t)(d0 + dl) * 4096 + n0 + tx * 2;
    float vx = 0.f, vy = 0.f;
#pragma unroll
    for (int k = 0; k < 4; ++k) {
      const unsigned dw = *(const unsigned*)(s0 + k * sstride + off);
      vx += bflo(dw);
      vy += bfhi(dw);
    }
    tile[dl][tx * 2] = vx;
    tile[dl][tx * 2 + 1] = vy;
    if (hT) {
      __hip_bfloat162 p;
      p.x = __float2bfloat16(vx);
      p.y = __float2bfloat16(vy);
      *(__hip_bfloat162*)(hT + (size_t)z * 256 * 4096 + off) = p;
    }
  }
  __syncthreads();
#pragma unroll
  for (int i = 0; i < 8; ++i) {
    const int c = ty + i * 8;  // n-local
    __hip_bfloat162 p;
    p.x = __float2bfloat16(tile[tx * 2][c]);
    p.y = __float2bfloat16(tile[tx * 2 + 1][c]);
    *(__hip_bfloat162*)(U + (size_t)(b * 4096 + n0 + c) * 1280 + uoff + d0 +
                        tx * 2) = p;
  }
}

// out = relu(U @ Wbig + b_lin), M=8192, K=1280, N=128
__global__ __launch_bounds__(256, 4) void gemm_proj(
    const bf16* __restrict__ U, const bf16* __restrict__ WbT,
    const float* __restrict__ blin, float* __restrict__ out) {
  __shared__ __align__(16) bf16 As[128 * 64];
  __shared__ __align__(16) bf16 Bs[64 * 64];
  const bf16* A = U + (size_t)blockIdx.x * 128 * 1280;
  const bf16* B = WbT + (size_t)blockIdx.y * 64 * 1280;
  v4f acc[4][2];
#pragma unroll
  for (int a = 0; a < 4; ++a)
#pragma unroll
    for (int b2 = 0; b2 < 2; ++b2) acc[a][b2] = (v4f){0.f, 0.f, 0.f, 0.f};
  mfma_loop<2, 64>(A, B, 1280, 1280, 1280, As, Bs, acc);
  const int tid = threadIdx.x, wave = tid >> 6, lane = tid & 63;
  const int quad = lane >> 4, r16 = lane & 15;
  const int wm = (wave >> 1) * 64, wn = (wave & 1) * 32;
  const int i0 = blockIdx.x * 128 + wm + quad * 4;
  const int j0 = blockIdx.y * 64 + wn + r16;
#pragma unroll
  for (int mi = 0; mi < 4; ++mi)
#pragma unroll
    for (int r = 0; r < 4; ++r) {
      const int i = i0 + mi * 16 + r;
#pragma unroll
      for (int ni = 0; ni < 2; ++ni) {
        const int j = j0 + ni * 16;
        out[(size_t)i * 128 + j] = fmaxf(acc[mi][ni][r] + blin[j], 0.f);
      }
    }
}

extern "C" void kernel_launch(void* const* d_in, const int* in_sizes, int n_in,
                              void* d_out, int out_size, void* d_ws,
                              size_t ws_size, hipStream_t stream) {
  const float* x = (const float*)d_in[0];
  const float* Wk = (const float*)d_in[1];
  const float* Wlin = (const float*)d_in[2];
  const float* blin = (const float*)d_in[3];
  float* out = (float*)d_out;
  char* w = (char*)d_ws;
  // workspace layout (bytes):
  bf16* hpart = (bf16*)(w);               // 4*4*256*4096*2    = 33554432
  bf16* h1T = (bf16*)(w + 33554432);      // 4 * 256*4096 * 2  = 8388608
  bf16* xhT = (bf16*)(w + 41943040);      // 2 * 256*4096 * 2  = 4194304
  bf16* U = (bf16*)(w + 46137344);        // 8192*1280 * 2     = 20971520
  bf16* WbT = (bf16*)(w + 67108864);      // 128*1280 * 2      = 327680
  float* sqv = (float*)(w + 67436544);    // 8192 * 4          = 32768
  // total ~67.5 MB

  prep<<<dim3(4096, 2), 256, 0, stream>>>(x, U, sqv);
  transk<<<dim3(64, 4, 2), 256, 0, stream>>>(x, xhT);
  wbig<<<dim3(640), 256, 0, stream>>>(Wk, Wlin, WbT);
  // pass 1: h1 = spline(x x^T) @ x   (V^T = xhT, shared by both kernels)
  fused_kh<<<dim3(64, 4, 2), 512, 0, stream>>>(U, sqv, xhT, xhT, 1, hpart);
  reduceT<<<dim3(64, 4, 4), 256, 0, stream>>>(hpart, U, h1T, 256);
  // pass 2: h2 = spline(x x^T) @ h1  (V^T per kernel chain from h1T)
  fused_kh<<<dim3(64, 4, 2), 512, 0, stream>>>(
      U, sqv, h1T, h1T + (size_t)256 * 4096, 2, hpart);
  reduceT<<<dim3(64, 4, 4), 256, 0, stream>>>(hpart, U, nullptr, 512);
  gemm_proj<<<dim3(64, 2), 256, 0, stream>>>(U, WbT, blin, out);
}